// Round 18
// baseline (22397.723 us; speedup 1.0000x reference)
//
#include <hip/hip_runtime.h>
#include <math.h>

#define BB 32
#define TT 2048
#define FF 16
#define CC 17
#define HH 64

typedef float v2f __attribute__((ext_vector_type(2)));
typedef float v4f __attribute__((ext_vector_type(4)));
typedef unsigned v4u __attribute__((ext_vector_type(4)));
typedef _Float16 h2 __attribute__((ext_vector_type(2)));

__device__ __forceinline__ float rl(float v, int lane) {
    return __int_as_float(__builtin_amdgcn_readlane(__float_as_int(v), lane));
}
__device__ __forceinline__ unsigned rlu(unsigned v, int lane) {
    return (unsigned)__builtin_amdgcn_readlane((int)v, lane);
}
__device__ __forceinline__ float uf(float v) {
    return __int_as_float(__builtin_amdgcn_readfirstlane(__float_as_int(v)));
}
__device__ __forceinline__ float ftanh(float x) {
    float e = __builtin_amdgcn_exp2f(x * 2.88539008177792681472f); // exp(2x)
    return 1.0f - 2.0f * __builtin_amdgcn_rcpf(e + 1.0f);
}
__device__ __forceinline__ float fdot2u(unsigned a, unsigned b, float c) {
    return __builtin_amdgcn_fdot2(__builtin_bit_cast(h2, a),
                                  __builtin_bit_cast(h2, b), c, false);
}
// pack (a,b) to f16x2, scaled by 2^8 (weights); RN; init-time only
__device__ __forceinline__ unsigned packw(float a, float b) {
    h2 p; p.x = (_Float16)(a * 256.0f); p.y = (_Float16)(b * 256.0f);
    return __builtin_bit_cast(unsigned, p);
}
// LDS-only barrier: no vmcnt(0) drain.
__device__ __forceinline__ void bar_lds() {
    asm volatile("s_waitcnt lgkmcnt(0)\n\ts_barrier" ::: "memory");
}
#define PIN(v) asm volatile("" : "+v"(v))

// R18 = R15 structure (two independent 8-wave halves per block, each running
// the R14 pipeline on its own batch element) WITHOUT R15's fatal
// waves_per_eu(4,4) (that forced a 64-VGPR cap -> spills, WRITE 16384->20352,
// FETCH +2GB). launch_bounds(1024) alone implies 4 waves/SIMD -> 128-reg
// budget; R14's per-wave state measured 92 arch VGPRs, so it fits.
// R17 proved the ILP lever (9.6ms-equivalent per element) but wasted it on a
// halved grid at 1 wave/SIMD; this keeps 16 blocks x 2 elements with 4
// waves/SIMD so each half's stall windows are filled by the other half.
__launch_bounds__(1024)
__global__ void ncde_main(const float* __restrict__ x,
                          const float* __restrict__ wi1, const float* __restrict__ bi1,
                          const float* __restrict__ wi2, const float* __restrict__ bi2,
                          const float* __restrict__ w_in, const float* __restrict__ b_in,
                          const float* __restrict__ w_hid, const float* __restrict__ b_hid,
                          const float* __restrict__ w_out, const float* __restrict__ b_out,
                          float* __restrict__ zT)
{
    const int bid  = blockIdx.x;
    const int tid  = threadIdx.x;
    const int ww   = tid >> 6;          // 0..15
    const int half = ww >> 3;           // 0 or 1
    const int w    = ww & 7;            // wave index within half
    const int l    = tid & 63;
    const int e    = 2 * bid + half;    // this half's batch element

    __shared__ float pht[2][4][64][12];               // per-half [layer][h-row][wave-col]
    __shared__ float pgqt[2][64][20];                 // per-half [h-row][(pg,a16) x 8 cols]
    __shared__ __align__(16) unsigned hbw[16][32];    // per-wave private packed h pairs

    const int cs = w ^ ((l >> 3) & 7);   // swizzled column (order-invariant sum)

    // ---- hidden weights: wave w owns k-slice [8w,8w+8), packed 4 u32/layer ----
    unsigned whp[4][4];
    #pragma unroll
    for (int kk = 0; kk < 4; ++kk) {
        int k = 8 * w + 2 * kk;
        whp[0][kk] = packw(w_in[k * HH + l],               w_in[(k + 1) * HH + l]);
        whp[1][kk] = packw(w_hid[(0 * HH + k) * HH + l],   w_hid[(0 * HH + k + 1) * HH + l]);
        whp[2][kk] = packw(w_hid[(1 * HH + k) * HH + l],   w_hid[(1 * HH + k + 1) * HH + l]);
        whp[3][kk] = packw(w_hid[(2 * HH + k) * HH + l],   w_hid[(2 * HH + k + 1) * HH + l]);
    }
    float bfold[4];
    bfold[0] = (w == 0) ? b_in[l] : 0.0f;
    bfold[1] = (w == 0) ? b_hid[0 * HH + l] : 0.0f;
    bfold[2] = (w == 0) ? b_hid[1 * HH + l] : 0.0f;
    bfold[3] = (w == 0) ? b_hid[2 * HH + l] : 0.0f;

    // ---- out-layer weights (cols c0,c1 per wave + c16 k-slice), packed ----
    const int c0 = 2 * w, c1 = 2 * w + 1;
    unsigned wo0p[32], wo1p[32], w16p[4];
    #pragma unroll
    for (int j = 0; j < 32; ++j) {
        wo0p[j] = packw(w_out[(2 * j) * (CC * HH) + l * CC + c0],
                        w_out[(2 * j + 1) * (CC * HH) + l * CC + c0]);
        wo1p[j] = packw(w_out[(2 * j) * (CC * HH) + l * CC + c1],
                        w_out[(2 * j + 1) * (CC * HH) + l * CC + c1]);
    }
    #pragma unroll
    for (int jj = 0; jj < 4; ++jj)
        w16p[jj] = packw(w_out[(8 * w + 2 * jj) * (CC * HH) + l * CC + 16],
                         w_out[(8 * w + 2 * jj + 1) * (CC * HH) + l * CC + 16]);
    float bo0  = b_out[l * CC + c0];
    float bo1  = b_out[l * CC + c1];
    float bo16 = (w == 0) ? b_out[l * CC + 16] : 0.0f;   // folded into per-half wave0

    #pragma unroll
    for (int j = 0; j < 32; ++j) { PIN(wo0p[j]); PIN(wo1p[j]); }
    #pragma unroll
    for (int jj = 0; jj < 4; ++jj) PIN(w16p[jj]);
    #pragma unroll
    for (int lay = 0; lay < 4; ++lay) {
        PIN(whp[lay][0]); PIN(whp[lay][1]); PIN(whp[lay][2]); PIN(whp[lay][3]);
    }
    PIN(bo0); PIN(bo1); PIN(bo16);

    // ---- z0 = relu(xa0 @ wi1 + bi1) @ wi2 + bi2 (f32, once, per half) ----
    float z;
    {
        float h0 = bi1[l];
        #pragma unroll
        for (int c = 1; c < CC; ++c)
            h0 = fmaf(x[(size_t)e * TT * FF + (c - 1)], wi1[c * HH + l], h0);
        h0 = fmaxf(h0, 0.0f);
        z = bi2[l];
        #pragma unroll
        for (int k = 0; k < 64; ++k)
            z = fmaf(rl(h0, k), wi2[k * HH + l], z);
    }
    if (w == 0) zT[(size_t)e * TT * HH + l] = z;

    // pack v*2^-8 into f16x2; every lane ends holding pair (v[2j],v[2j+1]), j=l>>1
    auto packb = [&](float v) -> unsigned {
        float hs = v * 0.00390625f;
        float pr = __shfl_xor(hs, 1);
        float a  = (l & 1) ? pr : hs;
        float bb = (l & 1) ? hs : pr;
        return __builtin_bit_cast(unsigned, __builtin_amdgcn_cvt_pkrtz(a, bb));
    };

    // ---- g(zin, xd) ----
    auto G = [&](float zin, float xd0, float xd1, float xd16) -> float {
        float cur = zin;
        #pragma unroll
        for (int L = 0; L < 4; ++L) {
            unsigned hp = packb(cur);
            float a0 = bfold[L], a1 = 0.0f;
            a0 = fdot2u(rlu(hp, 8 * w + 0), whp[L][0], a0);
            a1 = fdot2u(rlu(hp, 8 * w + 2), whp[L][1], a1);
            a0 = fdot2u(rlu(hp, 8 * w + 4), whp[L][2], a0);
            a1 = fdot2u(rlu(hp, 8 * w + 6), whp[L][3], a1);
            pht[half][L][l][cs] = a0 + a1;
            bar_lds();
            const float* row = &pht[half][L][l][0];
            v4f q0 = *reinterpret_cast<const v4f*>(row);       // cols 0..3 (any order)
            v4f q1 = *reinterpret_cast<const v4f*>(row + 4);   // cols 4..7
            float hsum = ((q0.x + q0.y) + (q0.z + q0.w)) + ((q1.x + q1.y) + (q1.z + q1.w));
            cur = fmaxf(hsum, 0.0f);
        }
        // out layer: private-LDS h broadcast (R14), no readlanes, no extra barrier
        unsigned hp = packb(cur);
        if ((l & 1) == 0) hbw[ww][l >> 1] = hp;
        float u0a = 0.f, u0b = 0.f, u0c = 0.f, u0d = 0.f;
        float u1a = 0.f, u1b = 0.f, u1c = 0.f, u1d = 0.f;
        #pragma unroll
        for (int j = 0; j < 8; ++j) {
            v4u q = *reinterpret_cast<const v4u*>(&hbw[ww][4 * j]);
            u0a = fdot2u(q.x, wo0p[4 * j + 0], u0a);
            u0b = fdot2u(q.y, wo0p[4 * j + 1], u0b);
            u0c = fdot2u(q.z, wo0p[4 * j + 2], u0c);
            u0d = fdot2u(q.w, wo0p[4 * j + 3], u0d);
            u1a = fdot2u(q.x, wo1p[4 * j + 0], u1a);
            u1b = fdot2u(q.y, wo1p[4 * j + 1], u1b);
            u1c = fdot2u(q.z, wo1p[4 * j + 2], u1c);
            u1d = fdot2u(q.w, wo1p[4 * j + 3], u1d);
        }
        v4u qc = *reinterpret_cast<const v4u*>(&hbw[ww][4 * w]);   // c16 k-slice pairs
        float a16a = fdot2u(qc.x, w16p[0], fdot2u(qc.z, w16p[2], bo16));
        float a16b = fdot2u(qc.y, w16p[1], fdot2u(qc.w, w16p[3], 0.0f));

        float u0 = ((u0a + u0b) + (u0c + u0d)) + bo0;
        float u1 = ((u1a + u1b) + (u1c + u1d)) + bo1;
        float pg = ftanh(u0) * xd0 + ftanh(u1) * xd1;
        *reinterpret_cast<v2f*>(&pgqt[half][l][2 * cs]) = (v2f){ pg, a16a + a16b };
        bar_lds();
        const float* prow = &pgqt[half][l][0];
        v4f r0 = *reinterpret_cast<const v4f*>(prow);
        v4f r1 = *reinterpret_cast<const v4f*>(prow + 4);
        v4f r2 = *reinterpret_cast<const v4f*>(prow + 8);
        v4f r3 = *reinterpret_cast<const v4f*>(prow + 12);
        float pgs  = ((r0.x + r0.z) + (r1.x + r1.z)) + ((r2.x + r2.z) + (r3.x + r3.z));
        float a16s = ((r0.y + r0.w) + (r1.y + r1.w)) + ((r2.y + r2.w) + (r3.y + r3.w));
        return fmaf(ftanh(a16s), xd16, pgs);
    };

    // ---- time scan (uniform x scalars in SGPRs) ----
    const float* xb = x + (size_t)e * TT * FF;
    const bool hasc0 = (w != 0);
    const int  f0 = 2 * w - 1;
    const int  f1 = 2 * w;
    float xp0  = hasc0 ? uf(xb[f0]) : 0.0f;
    float xp1  = uf(xb[f1]);
    float xp16 = uf(xb[15]);
    float xn0  = hasc0 ? uf(xb[FF + f0]) : 0.0f;
    float xn1  = uf(xb[FF + f1]);
    float xn16 = uf(xb[FF + 15]);
    float dc0  = hasc0 ? (xn0 - xp0) : 1.0f;
    float dc1  = xn1 - xp1;
    float dc16 = xn16 - xp16;
    float dp0 = dc0, dp1 = dc1, dp16 = dc16;
    xp0 = xn0; xp1 = xn1; xp16 = xn16;

    #pragma unroll 1
    for (int t = 0; t < TT - 1; ++t) {
        const float f43 = 4.0f / 3.0f;
        float x20  = dp0  + f43 * (dc0  - dp0);
        float x21  = dp1  + f43 * (dc1  - dp1);
        float x216 = dp16 + f43 * (dc16 - dp16);

        int tn = (t + 2 < TT) ? (t + 2) : (TT - 1);
        float yn0  = hasc0 ? uf(xb[tn * FF + f0]) : 0.0f;
        float yn1  = uf(xb[tn * FF + f1]);
        float yn16 = uf(xb[tn * FF + 15]);

        float k1 = G(z, dp0, dp1, dp16);
        float k2 = G(z + k1 * (1.0f / 3.0f), dc0, dc1, dc16);
        float k3 = G(z + (k2 - k1 * (1.0f / 3.0f)), x20, x21, x216);
        float k4 = G(z + (k1 - k2 + k3), dc0, dc1, dc16);
        z = z + 0.125f * (k1 + 3.0f * (k2 + k3) + k4);

        if (w == 0) zT[((size_t)e * TT + t + 1) * HH + l] = z;

        dp0 = dc0; dp1 = dc1; dp16 = dc16;
        dc0 = hasc0 ? (yn0 - xp0) : 1.0f;
        dc1 = yn1 - xp1;
        dc16 = yn16 - xp16;
        xp0 = yn0; xp1 = yn1; xp16 = yn16;
    }
}

// out = gelu_exact(zT) @ w_proj + b_proj ; mask = 0
__global__ void ncde_proj(const float* __restrict__ zT,
                          const float* __restrict__ w_proj, const float* __restrict__ b_proj,
                          float* __restrict__ out, float* __restrict__ mask)
{
    __shared__ float gz[16][64];
    const int blk = blockIdx.x;
    const int tid = threadIdx.x;
    const int r16 = tid >> 4, f = tid & 15;
    const int row0 = blk * 16;

    #pragma unroll
    for (int i = 0; i < 4; ++i) {
        int idx = tid + i * 256;
        int r = idx >> 6, k = idx & 63;
        float zv = zT[(size_t)(row0 + r) * HH + k];
        gz[r][k] = 0.5f * zv * (1.0f + erff(zv * 0.70710678118654752f));
    }
    __syncthreads();

    float acc = b_proj[f];
    #pragma unroll
    for (int k = 0; k < 64; ++k)
        acc = fmaf(gz[r16][k], w_proj[k * FF + f], acc);
    out[(size_t)(row0 + r16) * FF + f] = acc;
    if (f == 0) mask[row0 + r16] = 0.0f;
}

extern "C" void kernel_launch(void* const* d_in, const int* in_sizes, int n_in,
                              void* d_out, int out_size, void* d_ws, size_t ws_size,
                              hipStream_t stream)
{
    (void)in_sizes; (void)n_in; (void)d_ws; (void)ws_size; (void)out_size;
    const float* x      = (const float*)d_in[0];
    const float* wi1    = (const float*)d_in[1];
    const float* bi1    = (const float*)d_in[2];
    const float* wi2    = (const float*)d_in[3];
    const float* bi2    = (const float*)d_in[4];
    const float* w_in   = (const float*)d_in[5];
    const float* b_in   = (const float*)d_in[6];
    const float* w_hid  = (const float*)d_in[7];
    const float* b_hid  = (const float*)d_in[8];
    const float* w_out  = (const float*)d_in[9];
    const float* b_out  = (const float*)d_in[10];
    const float* w_proj = (const float*)d_in[11];
    const float* b_proj = (const float*)d_in[12];

    float* zT   = (float*)d_out;                       // B*T*H
    float* outp = zT + (size_t)BB * TT * HH;           // B*T*F
    float* mask = outp + (size_t)BB * TT * FF;         // B*T

    ncde_main<<<dim3(BB / 2), dim3(1024), 0, stream>>>(
        x, wi1, bi1, wi2, bi2, w_in, b_in, w_hid, b_hid, w_out, b_out, zT);
    ncde_proj<<<dim3((BB * TT) / 16), dim3(256), 0, stream>>>(
        zT, w_proj, b_proj, outp, mask);
}

// Round 19
// 12603.043 us; speedup vs baseline: 1.7772x; 1.7772x over previous
//
#include <hip/hip_runtime.h>
#include <math.h>

#define BB 32
#define TT 2048
#define FF 16
#define CC 17
#define HH 64

typedef float v2f __attribute__((ext_vector_type(2)));
typedef float v4f __attribute__((ext_vector_type(4)));
typedef unsigned v4u __attribute__((ext_vector_type(4)));
typedef _Float16 h2 __attribute__((ext_vector_type(2)));

__device__ __forceinline__ float rl(float v, int lane) {
    return __int_as_float(__builtin_amdgcn_readlane(__float_as_int(v), lane));
}
__device__ __forceinline__ unsigned rlu(unsigned v, int lane) {
    return (unsigned)__builtin_amdgcn_readlane((int)v, lane);
}
__device__ __forceinline__ float uf(float v) {
    return __int_as_float(__builtin_amdgcn_readfirstlane(__float_as_int(v)));
}
__device__ __forceinline__ float ftanh(float x) {
    float e = __builtin_amdgcn_exp2f(x * 2.88539008177792681472f); // exp(2x)
    return 1.0f - 2.0f * __builtin_amdgcn_rcpf(e + 1.0f);
}
__device__ __forceinline__ float fdot2u(unsigned a, unsigned b, float c) {
    return __builtin_amdgcn_fdot2(__builtin_bit_cast(h2, a),
                                  __builtin_bit_cast(h2, b), c, false);
}
// pack (a,b) to f16x2, scaled by 2^8 (weights); RN; init-time only
__device__ __forceinline__ unsigned packw(float a, float b) {
    h2 p; p.x = (_Float16)(a * 256.0f); p.y = (_Float16)(b * 256.0f);
    return __builtin_bit_cast(unsigned, p);
}
// LDS-only barrier: no vmcnt(0) drain.
__device__ __forceinline__ void bar_lds() {
    asm volatile("s_waitcnt lgkmcnt(0)\n\ts_barrier" ::: "memory");
}
#define PIN(v) asm volatile("" : "+v"(v))

// FINAL (== R14, measured 12.60 ms, absmax 24, VGPR 92, no spills/conflicts).
// Structure: 32 blocks (1/batch element) x 512 threads (8 waves, 2/SIMD --
// the only spill-free register regime on this allocator). Wave w owns:
// hidden k-slice [8w,8w+8) (f16x2-packed, pre-scaled 2^8), out columns
// (2w,2w+1) + c16 k-slice. Per G-call: 4 x [8-wide partial matvec ->
// transposed-LDS combine (2 x b128 reads/lane) -> barrier] + in-wave f16
// out-layer with per-wave private-LDS h broadcast (no readlanes) +
// transposed (pg,a16) combine. 5 LDS-only barriers (no vmcnt drain).
// Closed-out alternatives: more waves/fused elements spill (R5/R10/R15/
// R16/R18); 1-wave/SIMD exposes stalls (R13/R17); atomics serialize (R11);
// fewer barriers / fewer LDS ops / dehazarding each bought <=2% (R8/R12/R14).
__attribute__((amdgpu_waves_per_eu(2, 2)))
__launch_bounds__(512)
__global__ void ncde_main(const float* __restrict__ x,
                          const float* __restrict__ wi1, const float* __restrict__ bi1,
                          const float* __restrict__ wi2, const float* __restrict__ bi2,
                          const float* __restrict__ w_in, const float* __restrict__ b_in,
                          const float* __restrict__ w_hid, const float* __restrict__ b_hid,
                          const float* __restrict__ w_out, const float* __restrict__ b_out,
                          float* __restrict__ zT)
{
    const int b   = blockIdx.x;
    const int tid = threadIdx.x;
    const int w   = tid >> 6;
    const int l   = tid & 63;

    __shared__ float pht[4][64][12];                 // [layer][h-row][wave-col + pad]
    __shared__ float pgqt[64][20];                   // [h-row][(pg,a16) x 8 cols + pad]
    __shared__ __align__(16) unsigned hbw[8][32];    // per-wave private packed h pairs

    const int cs = w ^ ((l >> 3) & 7);   // swizzled column (order-invariant sum)

    // ---- hidden weights: wave w owns k-slice [8w,8w+8), packed 4 u32/layer ----
    unsigned whp[4][4];
    #pragma unroll
    for (int kk = 0; kk < 4; ++kk) {
        int k = 8 * w + 2 * kk;
        whp[0][kk] = packw(w_in[k * HH + l],               w_in[(k + 1) * HH + l]);
        whp[1][kk] = packw(w_hid[(0 * HH + k) * HH + l],   w_hid[(0 * HH + k + 1) * HH + l]);
        whp[2][kk] = packw(w_hid[(1 * HH + k) * HH + l],   w_hid[(1 * HH + k + 1) * HH + l]);
        whp[3][kk] = packw(w_hid[(2 * HH + k) * HH + l],   w_hid[(2 * HH + k + 1) * HH + l]);
    }
    float bfold[4];
    bfold[0] = (w == 0) ? b_in[l] : 0.0f;
    bfold[1] = (w == 0) ? b_hid[0 * HH + l] : 0.0f;
    bfold[2] = (w == 0) ? b_hid[1 * HH + l] : 0.0f;
    bfold[3] = (w == 0) ? b_hid[2 * HH + l] : 0.0f;

    // ---- out-layer weights (cols c0,c1 per wave + c16 k-slice), packed ----
    const int c0 = 2 * w, c1 = 2 * w + 1;
    unsigned wo0p[32], wo1p[32], w16p[4];
    #pragma unroll
    for (int j = 0; j < 32; ++j) {
        wo0p[j] = packw(w_out[(2 * j) * (CC * HH) + l * CC + c0],
                        w_out[(2 * j + 1) * (CC * HH) + l * CC + c0]);
        wo1p[j] = packw(w_out[(2 * j) * (CC * HH) + l * CC + c1],
                        w_out[(2 * j + 1) * (CC * HH) + l * CC + c1]);
    }
    #pragma unroll
    for (int jj = 0; jj < 4; ++jj)
        w16p[jj] = packw(w_out[(8 * w + 2 * jj) * (CC * HH) + l * CC + 16],
                         w_out[(8 * w + 2 * jj + 1) * (CC * HH) + l * CC + 16]);
    float bo0  = b_out[l * CC + c0];
    float bo1  = b_out[l * CC + c1];
    float bo16 = (w == 0) ? b_out[l * CC + 16] : 0.0f;   // folded into wave0 partial

    #pragma unroll
    for (int j = 0; j < 32; ++j) { PIN(wo0p[j]); PIN(wo1p[j]); }
    #pragma unroll
    for (int jj = 0; jj < 4; ++jj) PIN(w16p[jj]);
    #pragma unroll
    for (int lay = 0; lay < 4; ++lay) {
        PIN(whp[lay][0]); PIN(whp[lay][1]); PIN(whp[lay][2]); PIN(whp[lay][3]);
    }
    PIN(bo0); PIN(bo1); PIN(bo16);

    // ---- z0 = relu(xa0 @ wi1 + bi1) @ wi2 + bi2 (f32, once) ----
    float z;
    {
        float h0 = bi1[l];
        #pragma unroll
        for (int c = 1; c < CC; ++c)
            h0 = fmaf(x[(size_t)b * TT * FF + (c - 1)], wi1[c * HH + l], h0);
        h0 = fmaxf(h0, 0.0f);
        z = bi2[l];
        #pragma unroll
        for (int k = 0; k < 64; ++k)
            z = fmaf(rl(h0, k), wi2[k * HH + l], z);
    }
    if (w == 0) zT[(size_t)b * TT * HH + l] = z;

    // pack v*2^-8 into f16x2; every lane ends holding pair (v[2j],v[2j+1]), j=l>>1
    auto packb = [&](float v) -> unsigned {
        float hs = v * 0.00390625f;
        float pr = __shfl_xor(hs, 1);
        float a  = (l & 1) ? pr : hs;
        float bb = (l & 1) ? hs : pr;
        return __builtin_bit_cast(unsigned, __builtin_amdgcn_cvt_pkrtz(a, bb));
    };

    // ---- g(zin, xd) ----
    auto G = [&](float zin, float xd0, float xd1, float xd16) -> float {
        float cur = zin;
        #pragma unroll
        for (int L = 0; L < 4; ++L) {
            unsigned hp = packb(cur);
            float a0 = bfold[L], a1 = 0.0f;
            a0 = fdot2u(rlu(hp, 8 * w + 0), whp[L][0], a0);
            a1 = fdot2u(rlu(hp, 8 * w + 2), whp[L][1], a1);
            a0 = fdot2u(rlu(hp, 8 * w + 4), whp[L][2], a0);
            a1 = fdot2u(rlu(hp, 8 * w + 6), whp[L][3], a1);
            pht[L][l][cs] = a0 + a1;
            bar_lds();
            const float* row = &pht[L][l][0];
            v4f q0 = *reinterpret_cast<const v4f*>(row);       // cols 0..3 (any order)
            v4f q1 = *reinterpret_cast<const v4f*>(row + 4);   // cols 4..7
            float hsum = ((q0.x + q0.y) + (q0.z + q0.w)) + ((q1.x + q1.y) + (q1.z + q1.w));
            cur = fmaxf(hsum, 0.0f);
        }
        // out layer: publish packed h to THIS WAVE's private LDS row (no barrier
        // needed -- wave-internal ds ordering), then uniform-address b128 broadcasts.
        unsigned hp = packb(cur);
        if ((l & 1) == 0) hbw[w][l >> 1] = hp;
        float u0a = 0.f, u0b = 0.f, u0c = 0.f, u0d = 0.f;
        float u1a = 0.f, u1b = 0.f, u1c = 0.f, u1d = 0.f;
        #pragma unroll
        for (int j = 0; j < 8; ++j) {
            v4u q = *reinterpret_cast<const v4u*>(&hbw[w][4 * j]);
            u0a = fdot2u(q.x, wo0p[4 * j + 0], u0a);
            u0b = fdot2u(q.y, wo0p[4 * j + 1], u0b);
            u0c = fdot2u(q.z, wo0p[4 * j + 2], u0c);
            u0d = fdot2u(q.w, wo0p[4 * j + 3], u0d);
            u1a = fdot2u(q.x, wo1p[4 * j + 0], u1a);
            u1b = fdot2u(q.y, wo1p[4 * j + 1], u1b);
            u1c = fdot2u(q.z, wo1p[4 * j + 2], u1c);
            u1d = fdot2u(q.w, wo1p[4 * j + 3], u1d);
        }
        v4u qc = *reinterpret_cast<const v4u*>(&hbw[w][4 * w]);   // c16 k-slice pairs
        float a16a = fdot2u(qc.x, w16p[0], fdot2u(qc.z, w16p[2], bo16));
        float a16b = fdot2u(qc.y, w16p[1], fdot2u(qc.w, w16p[3], 0.0f));

        float u0 = ((u0a + u0b) + (u0c + u0d)) + bo0;
        float u1 = ((u1a + u1b) + (u1c + u1d)) + bo1;
        float pg = ftanh(u0) * xd0 + ftanh(u1) * xd1;
        *reinterpret_cast<v2f*>(&pgqt[l][2 * cs]) = (v2f){ pg, a16a + a16b };
        bar_lds();
        const float* prow = &pgqt[l][0];
        v4f r0 = *reinterpret_cast<const v4f*>(prow);
        v4f r1 = *reinterpret_cast<const v4f*>(prow + 4);
        v4f r2 = *reinterpret_cast<const v4f*>(prow + 8);
        v4f r3 = *reinterpret_cast<const v4f*>(prow + 12);
        float pgs  = ((r0.x + r0.z) + (r1.x + r1.z)) + ((r2.x + r2.z) + (r3.x + r3.z));
        float a16s = ((r0.y + r0.w) + (r1.y + r1.w)) + ((r2.y + r2.w) + (r3.y + r3.w));
        return fmaf(ftanh(a16s), xd16, pgs);
    };

    // ---- time scan (uniform x scalars in SGPRs) ----
    const float* xb = x + (size_t)b * TT * FF;
    const bool hasc0 = (w != 0);
    const int  f0 = 2 * w - 1;
    const int  f1 = 2 * w;
    float xp0  = hasc0 ? uf(xb[f0]) : 0.0f;
    float xp1  = uf(xb[f1]);
    float xp16 = uf(xb[15]);
    float xn0  = hasc0 ? uf(xb[FF + f0]) : 0.0f;
    float xn1  = uf(xb[FF + f1]);
    float xn16 = uf(xb[FF + 15]);
    float dc0  = hasc0 ? (xn0 - xp0) : 1.0f;
    float dc1  = xn1 - xp1;
    float dc16 = xn16 - xp16;
    float dp0 = dc0, dp1 = dc1, dp16 = dc16;
    xp0 = xn0; xp1 = xn1; xp16 = xn16;

    #pragma unroll 1
    for (int t = 0; t < TT - 1; ++t) {
        const float f43 = 4.0f / 3.0f;
        float x20  = dp0  + f43 * (dc0  - dp0);
        float x21  = dp1  + f43 * (dc1  - dp1);
        float x216 = dp16 + f43 * (dc16 - dp16);

        int tn = (t + 2 < TT) ? (t + 2) : (TT - 1);
        float yn0  = hasc0 ? uf(xb[tn * FF + f0]) : 0.0f;
        float yn1  = uf(xb[tn * FF + f1]);
        float yn16 = uf(xb[tn * FF + 15]);

        float k1 = G(z, dp0, dp1, dp16);
        float k2 = G(z + k1 * (1.0f / 3.0f), dc0, dc1, dc16);
        float k3 = G(z + (k2 - k1 * (1.0f / 3.0f)), x20, x21, x216);
        float k4 = G(z + (k1 - k2 + k3), dc0, dc1, dc16);
        z = z + 0.125f * (k1 + 3.0f * (k2 + k3) + k4);

        if (w == 0) zT[((size_t)b * TT + t + 1) * HH + l] = z;

        dp0 = dc0; dp1 = dc1; dp16 = dc16;
        dc0 = hasc0 ? (yn0 - xp0) : 1.0f;
        dc1 = yn1 - xp1;
        dc16 = yn16 - xp16;
        xp0 = yn0; xp1 = yn1; xp16 = yn16;
    }
}

// out = gelu_exact(zT) @ w_proj + b_proj ; mask = 0
__global__ void ncde_proj(const float* __restrict__ zT,
                          const float* __restrict__ w_proj, const float* __restrict__ b_proj,
                          float* __restrict__ out, float* __restrict__ mask)
{
    __shared__ float gz[16][64];
    const int blk = blockIdx.x;
    const int tid = threadIdx.x;
    const int r16 = tid >> 4, f = tid & 15;
    const int row0 = blk * 16;

    #pragma unroll
    for (int i = 0; i < 4; ++i) {
        int idx = tid + i * 256;
        int r = idx >> 6, k = idx & 63;
        float zv = zT[(size_t)(row0 + r) * HH + k];
        gz[r][k] = 0.5f * zv * (1.0f + erff(zv * 0.70710678118654752f));
    }
    __syncthreads();

    float acc = b_proj[f];
    #pragma unroll
    for (int k = 0; k < 64; ++k)
        acc = fmaf(gz[r16][k], w_proj[k * FF + f], acc);
    out[(size_t)(row0 + r16) * FF + f] = acc;
    if (f == 0) mask[row0 + r16] = 0.0f;
}

extern "C" void kernel_launch(void* const* d_in, const int* in_sizes, int n_in,
                              void* d_out, int out_size, void* d_ws, size_t ws_size,
                              hipStream_t stream)
{
    (void)in_sizes; (void)n_in; (void)d_ws; (void)ws_size; (void)out_size;
    const float* x      = (const float*)d_in[0];
    const float* wi1    = (const float*)d_in[1];
    const float* bi1    = (const float*)d_in[2];
    const float* wi2    = (const float*)d_in[3];
    const float* bi2    = (const float*)d_in[4];
    const float* w_in   = (const float*)d_in[5];
    const float* b_in   = (const float*)d_in[6];
    const float* w_hid  = (const float*)d_in[7];
    const float* b_hid  = (const float*)d_in[8];
    const float* w_out  = (const float*)d_in[9];
    const float* b_out  = (const float*)d_in[10];
    const float* w_proj = (const float*)d_in[11];
    const float* b_proj = (const float*)d_in[12];

    float* zT   = (float*)d_out;                       // B*T*H
    float* outp = zT + (size_t)BB * TT * HH;           // B*T*F
    float* mask = outp + (size_t)BB * TT * FF;         // B*T

    ncde_main<<<dim3(BB), dim3(512), 0, stream>>>(
        x, wi1, bi1, wi2, bi2, w_in, b_in, w_hid, b_hid, w_out, b_out, zT);
    ncde_proj<<<dim3((BB * TT) / 16), dim3(256), 0, stream>>>(
        zT, w_proj, b_proj, outp, mask);
}

// Round 20
// 11718.333 us; speedup vs baseline: 1.9113x; 1.0755x over previous
//
#include <hip/hip_runtime.h>
#include <math.h>

#define BB 32
#define TT 2048
#define FF 16
#define CC 17
#define HH 64

typedef float v2f __attribute__((ext_vector_type(2)));
typedef float v4f __attribute__((ext_vector_type(4)));
typedef unsigned v4u __attribute__((ext_vector_type(4)));
typedef _Float16 h2 __attribute__((ext_vector_type(2)));

__device__ __forceinline__ float rl(float v, int lane) {
    return __int_as_float(__builtin_amdgcn_readlane(__float_as_int(v), lane));
}
__device__ __forceinline__ float uf(float v) {
    return __int_as_float(__builtin_amdgcn_readfirstlane(__float_as_int(v)));
}
__device__ __forceinline__ float ftanh(float x) {
    float e = __builtin_amdgcn_exp2f(x * 2.88539008177792681472f); // exp(2x)
    return 1.0f - 2.0f * __builtin_amdgcn_rcpf(e + 1.0f);
}
__device__ __forceinline__ float fdot2u(unsigned a, unsigned b, float c) {
    return __builtin_amdgcn_fdot2(__builtin_bit_cast(h2, a),
                                  __builtin_bit_cast(h2, b), c, false);
}
// pack (a,b) to f16x2, scaled by 2^8 (weights); RN; init-time only
__device__ __forceinline__ unsigned packw(float a, float b) {
    h2 p; p.x = (_Float16)(a * 256.0f); p.y = (_Float16)(b * 256.0f);
    return __builtin_bit_cast(unsigned, p);
}
// LDS-only barrier: no vmcnt(0) drain.
__device__ __forceinline__ void bar_lds() {
    asm volatile("s_waitcnt lgkmcnt(0)\n\ts_barrier" ::: "memory");
}
#define PIN(v) asm volatile("" : "+v"(v))

// R20: role-split pipeline, 3 barriers/G (was 5).
//  wave 0: hidden layers 0,1 FULLY in-wave (lane l = column l; weights 64 u32
//          in regs; h via uniform-addr b128 LDS broadcast; no readlane/combine)
//  wave 1: hidden layers 2,3 (same)                       -> barrier A between
//  waves 2-7: out layer; wave v owns 3 columns (w7: c15+full c16) fed by the
//          published h4 (uniform b128) -> barrier B before, C after; 6-wide
//          pg combine read by all waves.
// R6 failed in-wave layers by STREAMING WEIGHTS from LDS; R7 by 4x128 regs.
// This holds 64 weight regs per chunk wave and <=96 per out wave.
__attribute__((amdgpu_waves_per_eu(2, 2)))
__launch_bounds__(512)
__global__ void ncde_main(const float* __restrict__ x,
                          const float* __restrict__ wi1, const float* __restrict__ bi1,
                          const float* __restrict__ wi2, const float* __restrict__ bi2,
                          const float* __restrict__ w_in, const float* __restrict__ b_in,
                          const float* __restrict__ w_hid, const float* __restrict__ b_hid,
                          const float* __restrict__ w_out, const float* __restrict__ b_out,
                          float* __restrict__ zT)
{
    const int b   = blockIdx.x;
    const int tid = threadIdx.x;
    const int w   = tid >> 6;
    const int l   = tid & 63;

    __shared__ __align__(16) unsigned zb[32];    // wave0-internal packed h stage
    __shared__ __align__(16) unsigned h2b[32];   // h2 (w0 -> w1), then w1-internal h3
    __shared__ __align__(16) unsigned hbuf[32];  // h4 (w1 -> out waves)
    __shared__ float pgqt[64][20];               // [h-row][6 pg cols + pad] (R14 stride)

    // role parameters (wave-uniform)
    const int nc    = (w >= 2) ? ((w < 7) ? 3 : 2) : 0;   // out columns owned
    const int cbase = (w < 7) ? 3 * (w - 2) : 15;         // first column (w>=2)

    // ---- weights: 96 u32, role-dependent content ----
    unsigned wreg[96];
    #pragma unroll
    for (int i = 0; i < 96; ++i) wreg[i] = 0u;
    float bA = 0.f, bB = 0.f, bC = 0.f;
    if (w == 0) {
        #pragma unroll
        for (int p = 0; p < 32; ++p) {
            wreg[p]      = packw(w_in[(2 * p) * HH + l],          w_in[(2 * p + 1) * HH + l]);
            wreg[32 + p] = packw(w_hid[(0 * HH + 2 * p) * HH + l], w_hid[(0 * HH + 2 * p + 1) * HH + l]);
        }
        bA = b_in[l];  bB = b_hid[l];
    } else if (w == 1) {
        #pragma unroll
        for (int p = 0; p < 32; ++p) {
            wreg[p]      = packw(w_hid[(1 * HH + 2 * p) * HH + l], w_hid[(1 * HH + 2 * p + 1) * HH + l]);
            wreg[32 + p] = packw(w_hid[(2 * HH + 2 * p) * HH + l], w_hid[(2 * HH + 2 * p + 1) * HH + l]);
        }
        bA = b_hid[HH + l];  bB = b_hid[2 * HH + l];
    } else {
        #pragma unroll
        for (int i = 0; i < 3; ++i) {
            if (i < nc) {
                int c = cbase + i;
                #pragma unroll
                for (int p = 0; p < 32; ++p)
                    wreg[32 * i + p] = packw(w_out[(2 * p) * (CC * HH) + l * CC + c],
                                             w_out[(2 * p + 1) * (CC * HH) + l * CC + c]);
            }
        }
        bA = b_out[l * CC + cbase];
        bB = b_out[l * CC + cbase + 1];
        if (nc == 3) bC = b_out[l * CC + cbase + 2];
    }
    #pragma unroll
    for (int i = 0; i < 96; ++i) PIN(wreg[i]);
    PIN(bA); PIN(bB); PIN(bC);

    // ---- z0 = relu(xa0 @ wi1 + bi1) @ wi2 + bi2 (f32, once, all waves) ----
    float z;
    {
        float h0 = bi1[l];
        #pragma unroll
        for (int c = 1; c < CC; ++c)
            h0 = fmaf(x[(size_t)b * TT * FF + (c - 1)], wi1[c * HH + l], h0);
        h0 = fmaxf(h0, 0.0f);
        z = bi2[l];
        #pragma unroll
        for (int k = 0; k < 64; ++k)
            z = fmaf(rl(h0, k), wi2[k * HH + l], z);
    }
    if (w == 7) zT[(size_t)b * TT * HH + l] = z;

    // pack v*2^-8 into f16x2; every lane ends holding pair (v[2j],v[2j+1]), j=l>>1
    auto packb = [&](float v) -> unsigned {
        float hs = v * 0.00390625f;
        float pr = __shfl_xor(hs, 1);
        float a  = (l & 1) ? pr : hs;
        float bb = (l & 1) ? hs : pr;
        return __builtin_bit_cast(unsigned, __builtin_amdgcn_cvt_pkrtz(a, bb));
    };

    // full 64-wide matvec column for lane l: h via uniform-address broadcasts
    auto LAYER = [&](const unsigned* Wc, float bias, const unsigned* hs) -> float {
        v4u q0 = *reinterpret_cast<const v4u*>(&hs[0]);
        v4u q1 = *reinterpret_cast<const v4u*>(&hs[4]);
        v4u q2 = *reinterpret_cast<const v4u*>(&hs[8]);
        v4u q3 = *reinterpret_cast<const v4u*>(&hs[12]);
        v4u q4 = *reinterpret_cast<const v4u*>(&hs[16]);
        v4u q5 = *reinterpret_cast<const v4u*>(&hs[20]);
        v4u q6 = *reinterpret_cast<const v4u*>(&hs[24]);
        v4u q7 = *reinterpret_cast<const v4u*>(&hs[28]);
        float a0 = bias, a1 = 0.f, a2 = 0.f, a3 = 0.f;
        a0 = fdot2u(q0.x, Wc[0],  a0); a1 = fdot2u(q0.y, Wc[1],  a1);
        a2 = fdot2u(q0.z, Wc[2],  a2); a3 = fdot2u(q0.w, Wc[3],  a3);
        a0 = fdot2u(q1.x, Wc[4],  a0); a1 = fdot2u(q1.y, Wc[5],  a1);
        a2 = fdot2u(q1.z, Wc[6],  a2); a3 = fdot2u(q1.w, Wc[7],  a3);
        a0 = fdot2u(q2.x, Wc[8],  a0); a1 = fdot2u(q2.y, Wc[9],  a1);
        a2 = fdot2u(q2.z, Wc[10], a2); a3 = fdot2u(q2.w, Wc[11], a3);
        a0 = fdot2u(q3.x, Wc[12], a0); a1 = fdot2u(q3.y, Wc[13], a1);
        a2 = fdot2u(q3.z, Wc[14], a2); a3 = fdot2u(q3.w, Wc[15], a3);
        a0 = fdot2u(q4.x, Wc[16], a0); a1 = fdot2u(q4.y, Wc[17], a1);
        a2 = fdot2u(q4.z, Wc[18], a2); a3 = fdot2u(q4.w, Wc[19], a3);
        a0 = fdot2u(q5.x, Wc[20], a0); a1 = fdot2u(q5.y, Wc[21], a1);
        a2 = fdot2u(q5.z, Wc[22], a2); a3 = fdot2u(q5.w, Wc[23], a3);
        a0 = fdot2u(q6.x, Wc[24], a0); a1 = fdot2u(q6.y, Wc[25], a1);
        a2 = fdot2u(q6.z, Wc[26], a2); a3 = fdot2u(q6.w, Wc[27], a3);
        a0 = fdot2u(q7.x, Wc[28], a0); a1 = fdot2u(q7.y, Wc[29], a1);
        a2 = fdot2u(q7.z, Wc[30], a2); a3 = fdot2u(q7.w, Wc[31], a3);
        return fmaxf((a0 + a1) + (a2 + a3), 0.0f);
    };
    // same, no relu, q's pre-loaded (out layer)
    auto DOT32 = [&](const unsigned* Wc, float bias,
                     v4u q0, v4u q1, v4u q2, v4u q3,
                     v4u q4, v4u q5, v4u q6, v4u q7) -> float {
        float a0 = bias, a1 = 0.f, a2 = 0.f, a3 = 0.f;
        a0 = fdot2u(q0.x, Wc[0],  a0); a1 = fdot2u(q0.y, Wc[1],  a1);
        a2 = fdot2u(q0.z, Wc[2],  a2); a3 = fdot2u(q0.w, Wc[3],  a3);
        a0 = fdot2u(q1.x, Wc[4],  a0); a1 = fdot2u(q1.y, Wc[5],  a1);
        a2 = fdot2u(q1.z, Wc[6],  a2); a3 = fdot2u(q1.w, Wc[7],  a3);
        a0 = fdot2u(q2.x, Wc[8],  a0); a1 = fdot2u(q2.y, Wc[9],  a1);
        a2 = fdot2u(q2.z, Wc[10], a2); a3 = fdot2u(q2.w, Wc[11], a3);
        a0 = fdot2u(q3.x, Wc[12], a0); a1 = fdot2u(q3.y, Wc[13], a1);
        a2 = fdot2u(q3.z, Wc[14], a2); a3 = fdot2u(q3.w, Wc[15], a3);
        a0 = fdot2u(q4.x, Wc[16], a0); a1 = fdot2u(q4.y, Wc[17], a1);
        a2 = fdot2u(q4.z, Wc[18], a2); a3 = fdot2u(q4.w, Wc[19], a3);
        a0 = fdot2u(q5.x, Wc[20], a0); a1 = fdot2u(q5.y, Wc[21], a1);
        a2 = fdot2u(q5.z, Wc[22], a2); a3 = fdot2u(q5.w, Wc[23], a3);
        a0 = fdot2u(q6.x, Wc[24], a0); a1 = fdot2u(q6.y, Wc[25], a1);
        a2 = fdot2u(q6.z, Wc[26], a2); a3 = fdot2u(q6.w, Wc[27], a3);
        a0 = fdot2u(q7.x, Wc[28], a0); a1 = fdot2u(q7.y, Wc[29], a1);
        a2 = fdot2u(q7.z, Wc[30], a2); a3 = fdot2u(q7.w, Wc[31], a3);
        return (a0 + a1) + (a2 + a3);
    };

    // ---- g(zin, xd[3]) : 3-barrier pipeline ----
    auto G = [&](float zin, float xd0, float xd1, float xd2) -> float {
        if (w == 0) {
            unsigned hp = packb(zin);
            if (!(l & 1)) zb[l >> 1] = hp;
            float h1v = LAYER(&wreg[0],  bA, zb);     // layer 0 (in-wave order)
            unsigned hp1 = packb(h1v);
            if (!(l & 1)) zb[l >> 1] = hp1;
            float h2v = LAYER(&wreg[32], bB, zb);     // layer 1
            unsigned hp2 = packb(h2v);
            if (!(l & 1)) h2b[l >> 1] = hp2;
        }
        bar_lds();   // A: h2 published
        if (w == 1) {
            float h3v = LAYER(&wreg[0],  bA, h2b);    // layer 2
            unsigned hp3 = packb(h3v);
            if (!(l & 1)) h2b[l >> 1] = hp3;          // internal reuse (wave-ordered)
            float h4v = LAYER(&wreg[32], bB, h2b);    // layer 3
            unsigned hp4 = packb(h4v);
            if (!(l & 1)) hbuf[l >> 1] = hp4;
        }
        bar_lds();   // B: h4 published
        if (w >= 2) {
            v4u q0 = *reinterpret_cast<const v4u*>(&hbuf[0]);
            v4u q1 = *reinterpret_cast<const v4u*>(&hbuf[4]);
            v4u q2 = *reinterpret_cast<const v4u*>(&hbuf[8]);
            v4u q3 = *reinterpret_cast<const v4u*>(&hbuf[12]);
            v4u q4 = *reinterpret_cast<const v4u*>(&hbuf[16]);
            v4u q5 = *reinterpret_cast<const v4u*>(&hbuf[20]);
            v4u q6 = *reinterpret_cast<const v4u*>(&hbuf[24]);
            v4u q7 = *reinterpret_cast<const v4u*>(&hbuf[28]);
            float u0 = DOT32(&wreg[0],  bA, q0, q1, q2, q3, q4, q5, q6, q7);
            float u1 = DOT32(&wreg[32], bB, q0, q1, q2, q3, q4, q5, q6, q7);
            float pg = ftanh(u0) * xd0 + ftanh(u1) * xd1;
            if (nc == 3) {
                float u2 = DOT32(&wreg[64], bC, q0, q1, q2, q3, q4, q5, q6, q7);
                pg = fmaf(ftanh(u2), xd2, pg);
            }
            pgqt[l][w - 2] = pg;
        }
        bar_lds();   // C: pg partials published
        const float* pr = &pgqt[l][0];
        v4f r0 = *reinterpret_cast<const v4f*>(pr);
        v2f r1 = *reinterpret_cast<const v2f*>(pr + 4);
        return ((r0.x + r0.y) + (r0.z + r0.w)) + (r1.x + r1.y);
    };

    // ---- time scan: wave w carries xd for its out columns (nc of them) ----
    const float* xb = x + (size_t)b * TT * FF;
    float xp[3] = {0, 0, 0}, dcv[3] = {0, 0, 0}, dpv[3] = {0, 0, 0};
    #pragma unroll
    for (int i = 0; i < 3; ++i) {
        if (i < nc) {
            int f = cbase + i - 1;              // feature; f<0 => time channel
            float v0 = (f < 0) ? 0.f : uf(xb[f]);
            float v1 = (f < 0) ? 0.f : uf(xb[FF + f]);
            dcv[i] = (f < 0) ? 1.0f : (v1 - v0);
            dpv[i] = dcv[i];
            xp[i]  = v1;
        }
    }

    #pragma unroll 1
    for (int t = 0; t < TT - 1; ++t) {
        const float f43 = 4.0f / 3.0f;
        float x2[3] = {0, 0, 0};
        #pragma unroll
        for (int i = 0; i < 3; ++i)
            if (i < nc) x2[i] = dpv[i] + f43 * (dcv[i] - dpv[i]);

        int tn = (t + 2 < TT) ? (t + 2) : (TT - 1);
        float yn[3] = {0, 0, 0};
        #pragma unroll
        for (int i = 0; i < 3; ++i) {
            if (i < nc) {
                int f = cbase + i - 1;
                yn[i] = (f < 0) ? 0.f : uf(xb[tn * FF + f]);
            }
        }

        float k1 = G(z, dpv[0], dpv[1], dpv[2]);
        float k2 = G(z + k1 * (1.0f / 3.0f), dcv[0], dcv[1], dcv[2]);
        float k3 = G(z + (k2 - k1 * (1.0f / 3.0f)), x2[0], x2[1], x2[2]);
        float k4 = G(z + (k1 - k2 + k3), dcv[0], dcv[1], dcv[2]);
        z = z + 0.125f * (k1 + 3.0f * (k2 + k3) + k4);

        if (w == 7) zT[((size_t)b * TT + t + 1) * HH + l] = z;

        #pragma unroll
        for (int i = 0; i < 3; ++i) {
            if (i < nc) {
                int f = cbase + i - 1;
                dpv[i] = dcv[i];
                dcv[i] = (f < 0) ? 1.0f : (yn[i] - xp[i]);
                xp[i]  = yn[i];
            }
        }
    }
}

// out = gelu_exact(zT) @ w_proj + b_proj ; mask = 0
__global__ void ncde_proj(const float* __restrict__ zT,
                          const float* __restrict__ w_proj, const float* __restrict__ b_proj,
                          float* __restrict__ out, float* __restrict__ mask)
{
    __shared__ float gz[16][64];
    const int blk = blockIdx.x;
    const int tid = threadIdx.x;
    const int r16 = tid >> 4, f = tid & 15;
    const int row0 = blk * 16;

    #pragma unroll
    for (int i = 0; i < 4; ++i) {
        int idx = tid + i * 256;
        int r = idx >> 6, k = idx & 63;
        float zv = zT[(size_t)(row0 + r) * HH + k];
        gz[r][k] = 0.5f * zv * (1.0f + erff(zv * 0.70710678118654752f));
    }
    __syncthreads();

    float acc = b_proj[f];
    #pragma unroll
    for (int k = 0; k < 64; ++k)
        acc = fmaf(gz[r16][k], w_proj[k * FF + f], acc);
    out[(size_t)(row0 + r16) * FF + f] = acc;
    if (f == 0) mask[row0 + r16] = 0.0f;
}

extern "C" void kernel_launch(void* const* d_in, const int* in_sizes, int n_in,
                              void* d_out, int out_size, void* d_ws, size_t ws_size,
                              hipStream_t stream)
{
    (void)in_sizes; (void)n_in; (void)d_ws; (void)ws_size; (void)out_size;
    const float* x      = (const float*)d_in[0];
    const float* wi1    = (const float*)d_in[1];
    const float* bi1    = (const float*)d_in[2];
    const float* wi2    = (const float*)d_in[3];
    const float* bi2    = (const float*)d_in[4];
    const float* w_in   = (const float*)d_in[5];
    const float* b_in   = (const float*)d_in[6];
    const float* w_hid  = (const float*)d_in[7];
    const float* b_hid  = (const float*)d_in[8];
    const float* w_out  = (const float*)d_in[9];
    const float* b_out  = (const float*)d_in[10];
    const float* w_proj = (const float*)d_in[11];
    const float* b_proj = (const float*)d_in[12];

    float* zT   = (float*)d_out;                       // B*T*H
    float* outp = zT + (size_t)BB * TT * HH;           // B*T*F
    float* mask = outp + (size_t)BB * TT * FF;         // B*T

    ncde_main<<<dim3(BB), dim3(512), 0, stream>>>(
        x, wi1, bi1, wi2, bi2, w_in, b_in, w_hid, b_hid, w_out, b_out, zT);
    ncde_proj<<<dim3((BB * TT) / 16), dim3(256), 0, stream>>>(
        zT, w_proj, b_proj, outp, mask);
}